// Round 12
// baseline (194.050 us; speedup 1.0000x reference)
//
#include <hip/hip_runtime.h>
#include <math.h>

typedef unsigned short u16;
typedef unsigned int u32;
typedef short s16x8 __attribute__((ext_vector_type(8)));
typedef float f32x4 __attribute__((ext_vector_type(4)));
typedef float f32x16 __attribute__((ext_vector_type(16)));
typedef u16 u16x4 __attribute__((ext_vector_type(4)));

#define DEVI __device__ __forceinline__

DEVI u16 f2bf(float f) {
  unsigned u = __builtin_bit_cast(unsigned, f);
  u += 0x7fffu + ((u >> 16) & 1u);
  return (u16)(u >> 16);
}

// pack two f32 -> 2x bf16 with round-half-up (+0x8000) via one v_perm_b32
DEVI u32 pkbf_hu(float a, float b) {
  const u32 ua = __builtin_bit_cast(u32, a) + 0x8000u;
  const u32 ub = __builtin_bit_cast(u32, b) + 0x8000u;
  return __builtin_amdgcn_perm(ub, ua, 0x07060302u);
}

DEVI f32x4 zero4() { f32x4 z; z[0]=0.f; z[1]=0.f; z[2]=0.f; z[3]=0.f; return z; }

DEVI float xor32_max(float x) { return fmaxf(x, __shfl_xor(x, 32, 64)); }
DEVI float xor32_sum(float x) { return x + __shfl_xor(x, 32, 64); }

#define MFMA16(a,b,c) __builtin_amdgcn_mfma_f32_16x16x32_bf16((a),(b),(c),0,0,0)
#define MFMA32(a,b,c) __builtin_amdgcn_mfma_f32_32x32x16_bf16((a),(b),(c),0,0,0)

#define GLD16(gp, lp) __builtin_amdgcn_global_load_lds( \
  (const __attribute__((address_space(1))) void*)(const void*)(gp), \
  (__attribute__((address_space(3))) void*)(void*)(lp), 16, 0, 0)

#define WAITVM(N) asm volatile("s_waitcnt vmcnt(" #N ")" ::: "memory")
#define WAITLG0() asm volatile("s_waitcnt lgkmcnt(0)" ::: "memory")
#define SBAR() __builtin_amdgcn_s_barrier()

// ---------------------------------------------------------------- prep kernels

__global__ __launch_bounds__(256) void prep_x(const float* __restrict__ x,
                                              u16* __restrict__ Aaug) {
  const int i = blockIdx.x * 256 + threadIdx.x;
  if (i >= 8192 * 192) return;
  const int row = i / 192, c4 = (i - row * 192) * 4;
  const float4 v = *(const float4*)(x + (size_t)row * 768 + c4);
  u16x4 o; o[0]=f2bf(v.x); o[1]=f2bf(v.y); o[2]=f2bf(v.z); o[3]=f2bf(v.w);
  *(u16x4*)(Aaug + (size_t)row * 896 + c4) = o;
}

__global__ __launch_bounds__(256) void prep_w(
    const float* __restrict__ Wqkv, const float* __restrict__ s1,
    const float* __restrict__ Wb, const float* __restrict__ Wup,
    const float* __restrict__ Wa, const float* __restrict__ Wdn,
    const float* __restrict__ Wr, const float* __restrict__ Wp,
    u16* __restrict__ Baug, u16* __restrict__ Wsm, u16* __restrict__ Wpj) {
  const int i = blockIdx.x * 256 + threadIdx.x;
  const int N1 = 2304 * 896, N2 = N1 + 256 * 768, N3 = N2 + 768 * 768;
  if (i < N1) {
    const int c = i / 896, kk = i - c * 896;
    float v;
    if (kk < 768)      v = Wqkv[(size_t)c * 768 + kk] * s1[c];
    else if (kk < 832) v = Wb[(size_t)c * 64 + (kk - 768)];
    else               v = Wup[(size_t)c * 64 + (kk - 832)];
    Baug[i] = f2bf(v);
  } else if (i < N2) {
    const int j = i - N1; const int r = j / 768, kk = j - r * 768;
    float v = 0.0f;
    if (r < 64)       v = Wa[(size_t)r * 768 + kk];
    else if (r < 128) v = Wdn[(size_t)(r - 64) * 768 + kk];
    else if (r < 200) v = Wr[(size_t)(r - 128) * 768 + kk];
    Wsm[j] = f2bf(v);
  } else if (i < N3) {
    const int j = i - N2;
    Wpj[j] = f2bf(Wp[j]);
  }
}

// ---------------------------------------------------------------- GEMM kernel
// 2-buffer (4 blocks/CU), depth-1 prefetch, counted vmcnt(4), stage-BEFORE-
// wait, two barriers, rolled loop. (Occupancy experiment vs the 3-buffer
// 72us config; unroll/single-barrier/4-buf/XCD-swizzle all measured WORSE.)

template <int MODE>
__global__ __launch_bounds__(256)
void gemm_mfma(const u16* __restrict__ A, int lda,
               const u16* __restrict__ Bt, int ldb,
               const float* __restrict__ p0, const float* __restrict__ p1,
               const float* __restrict__ p2,
               u16* __restrict__ ob0, u16* __restrict__ ob1, u16* __restrict__ ob2,
               float* __restrict__ of0,
               const float* __restrict__ gates) {
  __shared__ __align__(16) u16 lds[2][8192];
  __shared__ float glds[2][2][128];
  const int tid = threadIdx.x;
  const int w = tid >> 6, l = tid & 63;
  const int rl = l & 15, gq = l >> 4;
  const int wrow = (w >> 1) * 64, wcol = (w & 1) * 64;
  const int br = blockIdx.x, bc = blockIdx.y;
  const int nt = (MODE == 2) ? 28 : 24;

  const int srow = l >> 2;
  const int sslot = (l & 3) ^ ((srow >> 1) & 3);
  const u16* aSrc = A + (size_t)(br * 128 + w * 32 + srow) * lda + sslot * 8;
  const u16* bSrc = Bt + (size_t)(bc * 128 + w * 32 + srow) * ldb + sslot * 8;

  int tq = 0;
  if constexpr (MODE == 2) {
    const int g = bc * 2 + (w & 1);
    tq = g / 12;
  }

  auto kt_of = [&](int t) {
    if constexpr (MODE == 2) return (t < 2) ? 26 + t : ((t < 4) ? 22 + t : t - 4);
    else return t;
  };
  auto stage = [&](int kt, int buf) {
    const size_t k0 = (size_t)kt * 32;
    GLD16(aSrc + k0, &lds[buf][(w * 32) * 32]);
    GLD16(aSrc + k0 + (size_t)16 * lda, &lds[buf][(w * 32 + 16) * 32]);
    GLD16(bSrc + k0, &lds[buf][4096 + (w * 32) * 32]);
    GLD16(bSrc + k0 + (size_t)16 * ldb, &lds[buf][4096 + (w * 32 + 16) * 32]);
  };

  // prologue: stage tile 0, gate loads (MODE2)
  stage(kt_of(0), 0);
  if constexpr (MODE == 2) {
    const int gsel = tid >> 7, rr = tid & 127;
    const int gg = bc * 2 + gsel;
    const int tt = gg / 12, hh = gg % 12;
    const int f = hh * 3 + tt;
    const int ridx = (f / 12) * 24 + (f % 12) * 2;
    glds[gsel][0][rr] = gates[(size_t)(br * 128 + rr) * 72 + ridx];
    glds[gsel][1][rr] = gates[(size_t)(br * 128 + rr) * 72 + ridx + 1];
    WAITLG0();  // glds ds_writes visible before first barrier
  }

  f32x4 acc[4][4];
#pragma unroll
  for (int i = 0; i < 4; ++i)
#pragma unroll
    for (int j = 0; j < 4; ++j) acc[i][j] = zero4();

  for (int t = 0; t < nt; ++t) {
    const int buf = t & 1;
    if (t + 1 < nt) stage(kt_of(t + 1), buf ^ 1);  // issue BEFORE wait
    if (t < nt - 1) WAITVM(4);   // tile t drained; t+1 stays in flight
    else            WAITVM(0);
    SBAR();

    const int sl = gq ^ ((rl >> 1) & 3);
    s16x8 af[4], bfv[4];
#pragma unroll
    for (int fr = 0; fr < 4; ++fr) {
      const int row = wrow + fr * 16 + rl;
      af[fr] = *(const s16x8*)&lds[buf][row * 32 + sl * 8];
    }
#pragma unroll
    for (int fc = 0; fc < 4; ++fc) {
      const int row = wcol + fc * 16 + rl;
      bfv[fc] = *(const s16x8*)&lds[buf][4096 + row * 32 + sl * 8];
    }
#pragma unroll
    for (int fr = 0; fr < 4; ++fr)
#pragma unroll
      for (int fc = 0; fc < 4; ++fc)
        acc[fr][fc] = MFMA16(af[fr], bfv[fc], acc[fr][fc]);

    if constexpr (MODE == 2) {
      if (t == 1 || t == 3) {
        const int wsel = w & 1;
        const bool ad = (t == 1);
#pragma unroll
        for (int fr = 0; fr < 4; ++fr)
#pragma unroll
          for (int r = 0; r < 4; ++r) {
            const int rloc = wrow + fr * 16 + gq * 4 + r;
            const float gl = glds[wsel][0][rloc];
            float s;
            if (ad) { const float gp = glds[wsel][1][rloc]; s = (tq > 0) ? gp / gl : 0.0f; }
            else s = gl;
#pragma unroll
            for (int fc = 0; fc < 4; ++fc) acc[fr][fc][r] *= s;
          }
      }
    }
    SBAR();  // all waves done reading lds[buf] before it is restaged
  }

  if constexpr (MODE == 0) {
#pragma unroll
    for (int fc = 0; fc < 4; ++fc) {
      const int col = bc * 128 + wcol + fc * 16 + rl;
#pragma unroll
      for (int fr = 0; fr < 4; ++fr)
#pragma unroll
        for (int r = 0; r < 4; ++r) {
          const int grow = br * 128 + wrow + fr * 16 + gq * 4 + r;
          const float v = acc[fr][fc][r];
          if (col < 64) {
            ob0[(size_t)grow * 896 + 768 + col] = f2bf(v);
          } else if (col < 128) {
            const float u = v + p0[col - 64];
            const float gv = 0.5f * u * (1.0f + erff(u * 0.70710678118654752f));
            ob0[(size_t)grow * 896 + 832 + (col - 64)] = f2bf(gv);
          } else if (col < 200) {
            const float z = v + p1[col - 128];
            of0[(size_t)grow * 72 + (col - 128)] = 1.0f / (1.0f + expf(-z));
          }
        }
    }
  } else if constexpr (MODE == 1) {
#pragma unroll
    for (int fc = 0; fc < 4; ++fc) {
      const int col = bc * 128 + wcol + fc * 16 + rl;
      const float bb = p0[col], sc = p1[col], sf = p2[col];
#pragma unroll
      for (int fr = 0; fr < 4; ++fr)
#pragma unroll
        for (int r = 0; r < 4; ++r) {
          const int grow = br * 128 + wrow + fr * 16 + gq * 4 + r;
          of0[(size_t)grow * 768 + col] = (acc[fr][fc][r] + bb) * sc + sf;
        }
    }
  } else {
    const int wsel = w & 1;
    const int bq = br >> 3;
    const int n0 = (br & 7) * 128;
    const int cbase = bc * 128 + wcol;
    const int hh = (cbase % 768) / 64;
    float s1v[4], buv[4];
#pragma unroll
    for (int fc = 0; fc < 4; ++fc) {
      const int col = cbase + fc * 16 + rl;
      s1v[fc] = p0[col];
      buv[fc] = (tq > 0) ? p1[col] : 0.0f;
    }
    if (tq < 2) {
      u16* L = (u16*)&lds[0][0] + (size_t)w * 4096;
      u16* dst = (tq == 0) ? ob0 : ob1;
      const float osc = (tq == 0) ? 0.125f : 1.0f;
#pragma unroll
      for (int fr = 0; fr < 4; ++fr)
#pragma unroll
        for (int r = 0; r < 4; ++r) {
          const int nloc = fr * 16 + gq * 4 + r;
          const float gp = glds[wsel][1][wrow + nloc];
#pragma unroll
          for (int fc = 0; fc < 4; ++fc) {
            const int d = fc * 16 + rl;
            const float v = (acc[fr][fc][r] + s1v[fc] + gp * buv[fc]) * osc;
            L[nloc * 64 + (d ^ (gq << 4))] = f2bf(v);
          }
        }
      const size_t rowbase = (size_t)(bq * 12 + hh) * 1024 + n0 + wrow;
#pragma unroll
      for (int it = 0; it < 8; ++it) {
        const int nloc = it * 8 + (l >> 3);
        const int sl8 = l & 7;
        const s16x8 val =
            *(const s16x8*)&L[nloc * 64 + ((sl8 * 8) ^ (((nloc >> 2) & 3) << 4))];
        *(s16x8*)(dst + (rowbase + nloc) * 64 + sl8 * 8) = val;
      }
    } else {
      u16* L = (u16*)&lds[0][0] + (size_t)w * 4096;
#pragma unroll
      for (int fr = 0; fr < 4; ++fr)
#pragma unroll
        for (int r = 0; r < 4; ++r) {
          const int rloc = wrow + fr * 16 + gq * 4 + r;
          const float gp = glds[wsel][1][rloc];
          const int nloc = fr * 16 + gq * 4 + r;
#pragma unroll
          for (int fc = 0; fc < 4; ++fc) {
            const int d = fc * 16 + rl;
            const float v = acc[fr][fc][r] + s1v[fc] + gp * buv[fc];
            L[(d * 64 + nloc) ^ ((d & 7) << 3)] = f2bf(v);
          }
        }
      const int nw = n0 + wrow;
#pragma unroll
      for (int it = 0; it < 8; ++it) {
        const int d = it * 8 + (l >> 3);
        const int slot = l & 7;
        const s16x8 val = *(const s16x8*)&L[d * 64 + ((slot ^ (d & 7)) << 3)];
        *(s16x8*)(ob2 + ((size_t)(bq * 12 + hh) * 64 + d) * 1024 + nw + slot * 8) = val;
      }
    }
  }
}

// ---------------------------------------------------------------- attention
// Swapped-QK^T 32x32; 3-buffer depth-2 counted-vmcnt pipeline (proven shape).

__global__ __launch_bounds__(256)
void attn2_kernel(const u16* __restrict__ Q, const u16* __restrict__ K,
                  const u16* __restrict__ VT, u16* __restrict__ AO) {
  __shared__ __align__(16) u16 kv[3][8192];  // [buf][ K 64x64 | VT 64x64 ]
  const int tid = threadIdx.x, w = tid >> 6, l = tid & 63;
  const int l31 = l & 31, hi = l >> 5;
  const int bh = blockIdx.x % 96, qt = blockIdx.x / 96;
  const size_t kb = (size_t)bh * (1024 * 64);
  const float LOG2E = 1.4426950408889634f;
  const float THR = 5.545177f;

  const int q0 = qt * 128 + w * 32;
  s16x8 qf[4];
  {
    const u16* qp = Q + kb + (size_t)(q0 + l31) * 64 + hi * 8;
#pragma unroll
    for (int ks = 0; ks < 4; ++ks) qf[ks] = *(const s16x8*)(qp + ks * 16);
  }

  const int srow = l >> 3;
  const int sslot = (l & 7) ^ srow;
  const u16* kSrc = K + kb + (size_t)(w * 16 + srow) * 64 + sslot * 8;
  const u16* vSrc = VT + kb + (size_t)(w * 16 + srow) * 1024 + sslot * 8;
  auto stage = [&](int t, int buf) {
    const int kv0 = t * 64;
    GLD16(kSrc + (size_t)kv0 * 64, &kv[buf][(w * 16) * 64]);
    GLD16(kSrc + (size_t)kv0 * 64 + 8 * 64, &kv[buf][(w * 16 + 8) * 64]);
    GLD16(vSrc + kv0, &kv[buf][4096 + (w * 16) * 64]);
    GLD16(vSrc + kv0 + 8 * 1024, &kv[buf][4096 + (w * 16 + 8) * 64]);
  };

  f32x16 o0, o1;
#pragma unroll
  for (int r = 0; r < 16; ++r) { o0[r] = 0.f; o1[r] = 0.f; }
  float m = -1.0e30f, lsum = 0.f;

  const int swz = l31 & 7;

  stage(0, 0);
  stage(1, 1);

  for (int t = 0; t < 16; ++t) {
    const int buf = t % 3;
    if (t + 2 < 16) stage(t + 2, (t + 2) % 3);
    if (t < 14)       WAITVM(8);
    else if (t == 14) WAITVM(4);
    else              WAITVM(0);
    SBAR();

    // ---- QK^T: S^T[kv][q]; lane q-col = l31; kv(r,hi) = (r&3)+8*(r>>2)+4*hi
    f32x16 sA, sB;
#pragma unroll
    for (int r = 0; r < 16; ++r) { sA[r] = 0.f; sB[r] = 0.f; }
#pragma unroll
    for (int ks = 0; ks < 4; ++ks) {
      const int slot = (ks * 2 + hi) ^ swz;
      const s16x8 k0 = *(const s16x8*)&kv[buf][l31 * 64 + slot * 8];
      const s16x8 k1 = *(const s16x8*)&kv[buf][(32 + l31) * 64 + slot * 8];
      sA = MFMA32(k0, qf[ks], sA);
      sB = MFMA32(k1, qf[ks], sB);
    }

    // ---- online softmax (per-lane: one q = l31)
    float pm = sA[0];
#pragma unroll
    for (int r = 1; r < 16; ++r) pm = fmaxf(pm, sA[r]);
#pragma unroll
    for (int r = 0; r < 16; ++r) pm = fmaxf(pm, sB[r]);
    pm = xor32_max(pm);

    const bool need = pm > m + THR;
    if (__any(need)) {
      const float mnew = need ? pm : m;
      const float corr = __builtin_amdgcn_exp2f((m - mnew) * LOG2E);
      m = mnew;
      lsum *= corr;
#pragma unroll
      for (int r = 0; r < 16; ++r) {
        const int qrow = (r & 3) + 8 * (r >> 2) + 4 * hi;
        const float cr = __shfl(corr, qrow, 64);
        o0[r] *= cr; o1[r] *= cr;
      }
    }

    const float mL = m * LOG2E;
    float ps = 0.f;
#pragma unroll
    for (int r = 0; r < 16; ++r) {
      const float p = __builtin_amdgcn_exp2f(__builtin_fmaf(sA[r], LOG2E, -mL));
      sA[r] = p; ps += p;
    }
#pragma unroll
    for (int r = 0; r < 16; ++r) {
      const float p = __builtin_amdgcn_exp2f(__builtin_fmaf(sB[r], LOG2E, -mL));
      sB[r] = p; ps += p;
    }
    lsum += xor32_sum(ps);

    // ---- P -> bf16 A-fragments via perm-pack + shfl_xor(32) + per-half select
    s16x8 pf[4];
#pragma unroll
    for (int s = 0; s < 4; ++s) {
      const f32x16 P = (s < 2) ? sA : sB;
      const int b = 8 * (s & 1);
      const u32 A0 = pkbf_hu(P[b + 0], P[b + 1]);
      const u32 A1 = pkbf_hu(P[b + 2], P[b + 3]);
      const u32 A2 = pkbf_hu(P[b + 4], P[b + 5]);
      const u32 A3 = pkbf_hu(P[b + 6], P[b + 7]);
      const u32 B0 = (u32)__shfl_xor((int)A0, 32, 64);
      const u32 B1 = (u32)__shfl_xor((int)A1, 32, 64);
      const u32 B2 = (u32)__shfl_xor((int)A2, 32, 64);
      const u32 B3 = (u32)__shfl_xor((int)A3, 32, 64);
      union { u32 u[4]; s16x8 v; } pk;
      pk.u[0] = hi ? B2 : A0;
      pk.u[1] = hi ? B3 : A1;
      pk.u[2] = hi ? A2 : B0;
      pk.u[3] = hi ? A3 : B1;
      pf[s] = pk.v;
    }

    // ---- PV
#pragma unroll
    for (int s = 0; s < 4; ++s) {
      const int slot = (s * 2 + hi) ^ swz;
      const s16x8 v0 = *(const s16x8*)&kv[buf][4096 + l31 * 64 + slot * 8];
      const s16x8 v1 = *(const s16x8*)&kv[buf][4096 + (32 + l31) * 64 + slot * 8];
      o0 = MFMA32(pf[s], v0, o0);
      o1 = MFMA32(pf[s], v1, o1);
    }
    SBAR();
  }

  // ---- epilogue
  const float invl = 1.0f / lsum;
  const int bq = bh / 12, h = bh % 12;
#pragma unroll
  for (int r = 0; r < 16; ++r) {
    const int qrow = (r & 3) + 8 * (r >> 2) + 4 * hi;
    const float ir = __shfl(invl, qrow, 64);
    const int n = q0 + qrow;
    u16* dst = AO + ((size_t)bq * 1024 + n) * 768 + h * 64 + l31;
    dst[0]  = f2bf(o0[r] * ir);
    dst[32] = f2bf(o1[r] * ir);
  }
}

// ---------------------------------------------------------------- launch

extern "C" void kernel_launch(void* const* d_in, const int* in_sizes, int n_in,
                              void* d_out, int out_size, void* d_ws, size_t ws_size,
                              hipStream_t stream) {
  (void)in_sizes; (void)n_in; (void)out_size; (void)ws_size;
  const float* x    = (const float*)d_in[0];
  const float* Wqkv = (const float*)d_in[1];
  const float* s1   = (const float*)d_in[2];
  const float* sh1  = (const float*)d_in[3];
  const float* Wa   = (const float*)d_in[4];
  const float* Wb   = (const float*)d_in[5];
  const float* Wr   = (const float*)d_in[6];
  const float* brt  = (const float*)d_in[7];
  const float* Wdn  = (const float*)d_in[8];
  const float* bdn  = (const float*)d_in[9];
  const float* Wup  = (const float*)d_in[10];
  const float* bup  = (const float*)d_in[11];
  const float* Wp   = (const float*)d_in[12];
  const float* bpj  = (const float*)d_in[13];
  const float* sc2  = (const float*)d_in[14];
  const float* sf2  = (const float*)d_in[15];
  float* out = (float*)d_out;

  char* ws = (char*)d_ws;
  size_t off = 0;
  auto take = [&](size_t bytes) -> void* {
    void* p = ws + off;
    off = (off + bytes + 255) & ~(size_t)255;
    return p;
  };
  u16* Aaug = (u16*)take(8192UL * 896 * 2);
  u16* Baug = (u16*)take(2304UL * 896 * 2);
  u16* Wsm  = (u16*)take(256UL * 768 * 2);
  u16* Wpj  = (u16*)take(768UL * 768 * 2);
  float* gates = (float*)take(8192UL * 72 * 4);
  u16* qb  = (u16*)take(96UL * 1024 * 64 * 2);
  u16* kbf = (u16*)take(96UL * 1024 * 64 * 2);
  u16* vtb = (u16*)take(96UL * 64 * 1024 * 2);
  u16* ao  = (u16*)take(8192UL * 768 * 2);

  prep_x<<<dim3(6144), dim3(256), 0, stream>>>(x, Aaug);
  prep_w<<<dim3(11136), dim3(256), 0, stream>>>(Wqkv, s1, Wb, Wup, Wa, Wdn, Wr, Wp,
                                                Baug, Wsm, Wpj);
  gemm_mfma<0><<<dim3(64, 2), dim3(256), 0, stream>>>(
      Aaug, 896, Wsm, 768, bdn, brt, nullptr, Aaug, nullptr, nullptr, gates, nullptr);
  gemm_mfma<2><<<dim3(64, 18), dim3(256), 0, stream>>>(
      Aaug, 896, Baug, 896, sh1, bup, nullptr, qb, kbf, vtb, nullptr, gates);
  attn2_kernel<<<dim3(768), dim3(256), 0, stream>>>(qb, kbf, vtb, ao);
  gemm_mfma<1><<<dim3(64, 6), dim3(256), 0, stream>>>(
      ao, 768, Wpj, 768, bpj, sc2, sf2, nullptr, nullptr, nullptr, out, nullptr);
}

// Round 13
// 179.834 us; speedup vs baseline: 1.0790x; 1.0790x over previous
//
#include <hip/hip_runtime.h>
#include <math.h>

typedef unsigned short u16;
typedef unsigned int u32;
typedef short s16x8 __attribute__((ext_vector_type(8)));
typedef float f32x4 __attribute__((ext_vector_type(4)));
typedef float f32x16 __attribute__((ext_vector_type(16)));
typedef u16 u16x4 __attribute__((ext_vector_type(4)));

#define DEVI __device__ __forceinline__

DEVI u16 f2bf(float f) {
  unsigned u = __builtin_bit_cast(unsigned, f);
  u += 0x7fffu + ((u >> 16) & 1u);
  return (u16)(u >> 16);
}

// pack two f32 -> 2x bf16 with round-half-up (+0x8000) via one v_perm_b32
DEVI u32 pkbf_hu(float a, float b) {
  const u32 ua = __builtin_bit_cast(u32, a) + 0x8000u;
  const u32 ub = __builtin_bit_cast(u32, b) + 0x8000u;
  return __builtin_amdgcn_perm(ub, ua, 0x07060302u);
}

DEVI f32x4 zero4() { f32x4 z; z[0]=0.f; z[1]=0.f; z[2]=0.f; z[3]=0.f; return z; }

DEVI float xor32_max(float x) { return fmaxf(x, __shfl_xor(x, 32, 64)); }
DEVI float xor32_sum(float x) { return x + __shfl_xor(x, 32, 64); }

#define MFMA16(a,b,c) __builtin_amdgcn_mfma_f32_16x16x32_bf16((a),(b),(c),0,0,0)
#define MFMA32(a,b,c) __builtin_amdgcn_mfma_f32_32x32x16_bf16((a),(b),(c),0,0,0)

#define GLD16(gp, lp) __builtin_amdgcn_global_load_lds( \
  (const __attribute__((address_space(1))) void*)(const void*)(gp), \
  (__attribute__((address_space(3))) void*)(void*)(lp), 16, 0, 0)

#define WAITVM(N) asm volatile("s_waitcnt vmcnt(" #N ")" ::: "memory")
#define WAITLG0() asm volatile("s_waitcnt lgkmcnt(0)" ::: "memory")
#define SBAR() __builtin_amdgcn_s_barrier()

// ---------------------------------------------------------------- prep kernels

__global__ __launch_bounds__(256) void prep_x(const float* __restrict__ x,
                                              u16* __restrict__ Aaug) {
  const int i = blockIdx.x * 256 + threadIdx.x;
  if (i >= 8192 * 192) return;
  const int row = i / 192, c4 = (i - row * 192) * 4;
  const float4 v = *(const float4*)(x + (size_t)row * 768 + c4);
  u16x4 o; o[0]=f2bf(v.x); o[1]=f2bf(v.y); o[2]=f2bf(v.z); o[3]=f2bf(v.w);
  *(u16x4*)(Aaug + (size_t)row * 896 + c4) = o;
}

__global__ __launch_bounds__(256) void prep_w(
    const float* __restrict__ Wqkv, const float* __restrict__ s1,
    const float* __restrict__ Wb, const float* __restrict__ Wup,
    const float* __restrict__ Wa, const float* __restrict__ Wdn,
    const float* __restrict__ Wr, const float* __restrict__ Wp,
    u16* __restrict__ Baug, u16* __restrict__ Wsm, u16* __restrict__ Wpj) {
  const int i = blockIdx.x * 256 + threadIdx.x;
  const int N1 = 2304 * 896, N2 = N1 + 256 * 768, N3 = N2 + 768 * 768;
  if (i < N1) {
    const int c = i / 896, kk = i - c * 896;
    float v;
    if (kk < 768)      v = Wqkv[(size_t)c * 768 + kk] * s1[c];
    else if (kk < 832) v = Wb[(size_t)c * 64 + (kk - 768)];
    else               v = Wup[(size_t)c * 64 + (kk - 832)];
    Baug[i] = f2bf(v);
  } else if (i < N2) {
    const int j = i - N1; const int r = j / 768, kk = j - r * 768;
    float v = 0.0f;
    if (r < 64)       v = Wa[(size_t)r * 768 + kk];
    else if (r < 128) v = Wdn[(size_t)(r - 64) * 768 + kk];
    else if (r < 200) v = Wr[(size_t)(r - 128) * 768 + kk];
    Wsm[j] = f2bf(v);
  } else if (i < N3) {
    const int j = i - N2;
    Wpj[j] = f2bf(Wp[j]);
  }
}

// ---------------------------------------------------------------- GEMM kernel
// Proven loop shape (174us anchor): 3-buffer, depth-2, stage-BEFORE-wait,
// counted vmcnt, two barriers, rolled loop.
// MODE2 only: tile 256x128, 8 waves (512 thr) -> 2 blocks x 8 = 16 waves/CU.
// MODE0/1: unchanged 128x128, 4 waves, 3 blocks/CU.

template <int MODE>
__global__ __launch_bounds__((MODE == 2) ? 512 : 256)
void gemm_mfma(const u16* __restrict__ A, int lda,
               const u16* __restrict__ Bt, int ldb,
               const float* __restrict__ p0, const float* __restrict__ p1,
               const float* __restrict__ p2,
               u16* __restrict__ ob0, u16* __restrict__ ob1, u16* __restrict__ ob2,
               float* __restrict__ of0,
               const float* __restrict__ gates) {
  constexpr int BM   = (MODE == 2) ? 256 : 128;     // tile rows
  constexpr int BUFU = (MODE == 2) ? 12288 : 8192;  // u16 per buffer
  constexpr int BOFF = (MODE == 2) ? 8192 : 4096;   // B region offset (u16)
  constexpr int nt   = (MODE == 2) ? 28 : 24;

  __shared__ __align__(16) u16 lds[3][BUFU];
  __shared__ float glds[2][2][BM];
  const int tid = threadIdx.x;
  const int w = tid >> 6, l = tid & 63;
  const int rl = l & 15, gq = l >> 4;
  const int wrow = (w >> 1) * 64, wcol = (w & 1) * 64;
  const int br = blockIdx.x, bc = blockIdx.y;

  const int srow = l >> 2;
  const int sslot = (l & 3) ^ ((srow >> 1) & 3);
  const u16* aSrc = A + (size_t)(br * BM + w * 32 + srow) * lda + sslot * 8;
  const int bwrow = (MODE == 2) ? w * 16 : w * 32;
  const u16* bSrc = Bt + (size_t)(bc * 128 + bwrow + srow) * ldb + sslot * 8;

  int tq = 0;
  if constexpr (MODE == 2) {
    const int g = bc * 2 + (w & 1);
    tq = g / 12;
  }

  auto kt_of = [&](int t) {
    if constexpr (MODE == 2) return (t < 2) ? 26 + t : ((t < 4) ? 22 + t : t - 4);
    else return t;
  };
  auto stage = [&](int kt, int buf) {
    const size_t k0 = (size_t)kt * 32;
    GLD16(aSrc + k0, &lds[buf][(w * 32) * 32]);
    GLD16(aSrc + k0 + (size_t)16 * lda, &lds[buf][(w * 32 + 16) * 32]);
    if constexpr (MODE == 2) {
      GLD16(bSrc + k0, &lds[buf][BOFF + (w * 16) * 32]);
    } else {
      GLD16(bSrc + k0, &lds[buf][BOFF + (w * 32) * 32]);
      GLD16(bSrc + k0 + (size_t)16 * ldb, &lds[buf][BOFF + (w * 32 + 16) * 32]);
    }
  };

  // prologue: stage 2 tiles, gate loads (MODE2)
  stage(kt_of(0), 0);
  stage(kt_of(1), 1);
  if constexpr (MODE == 2) {
    const int gsel = tid >> 8, rr = tid & 255;   // 512 threads: 2 x 256 rows
    const int gg = bc * 2 + gsel;
    const int tt = gg / 12, hh = gg % 12;
    const int f = hh * 3 + tt;
    const int ridx = (f / 12) * 24 + (f % 12) * 2;
    glds[gsel][0][rr] = gates[(size_t)(br * BM + rr) * 72 + ridx];
    glds[gsel][1][rr] = gates[(size_t)(br * BM + rr) * 72 + ridx + 1];
    WAITLG0();  // glds ds_writes visible before first barrier
  }

  f32x4 acc[4][4];
#pragma unroll
  for (int i = 0; i < 4; ++i)
#pragma unroll
    for (int j = 0; j < 4; ++j) acc[i][j] = zero4();

  for (int t = 0; t < nt; ++t) {
    const int buf = t % 3;
    if (t + 2 < nt) stage(kt_of(t + 2), (t + 2) % 3);  // issue BEFORE wait
    if constexpr (MODE == 2) {
      if (t < nt - 2)       WAITVM(6);   // 3 loads/stage
      else if (t == nt - 2) WAITVM(3);
      else                  WAITVM(0);
    } else {
      if (t < nt - 2)       WAITVM(8);   // 4 loads/stage
      else if (t == nt - 2) WAITVM(4);
      else                  WAITVM(0);
    }
    SBAR();

    const int sl = gq ^ ((rl >> 1) & 3);
    s16x8 af[4], bfv[4];
#pragma unroll
    for (int fr = 0; fr < 4; ++fr) {
      const int row = wrow + fr * 16 + rl;
      af[fr] = *(const s16x8*)&lds[buf][row * 32 + sl * 8];
    }
#pragma unroll
    for (int fc = 0; fc < 4; ++fc) {
      const int row = wcol + fc * 16 + rl;
      bfv[fc] = *(const s16x8*)&lds[buf][BOFF + row * 32 + sl * 8];
    }
#pragma unroll
    for (int fr = 0; fr < 4; ++fr)
#pragma unroll
      for (int fc = 0; fc < 4; ++fc)
        acc[fr][fc] = MFMA16(af[fr], bfv[fc], acc[fr][fc]);

    if constexpr (MODE == 2) {
      if (t == 1 || t == 3) {
        const int wsel = w & 1;
        const bool ad = (t == 1);
#pragma unroll
        for (int fr = 0; fr < 4; ++fr)
#pragma unroll
          for (int r = 0; r < 4; ++r) {
            const int rloc = wrow + fr * 16 + gq * 4 + r;
            const float gl = glds[wsel][0][rloc];
            float s;
            if (ad) { const float gp = glds[wsel][1][rloc]; s = (tq > 0) ? gp / gl : 0.0f; }
            else s = gl;
#pragma unroll
            for (int fc = 0; fc < 4; ++fc) acc[fr][fc][r] *= s;
          }
      }
    }
    SBAR();  // all waves done reading lds[buf] before it is restaged
  }

  if constexpr (MODE == 0) {
#pragma unroll
    for (int fc = 0; fc < 4; ++fc) {
      const int col = bc * 128 + wcol + fc * 16 + rl;
#pragma unroll
      for (int fr = 0; fr < 4; ++fr)
#pragma unroll
        for (int r = 0; r < 4; ++r) {
          const int grow = br * 128 + wrow + fr * 16 + gq * 4 + r;
          const float v = acc[fr][fc][r];
          if (col < 64) {
            ob0[(size_t)grow * 896 + 768 + col] = f2bf(v);
          } else if (col < 128) {
            const float u = v + p0[col - 64];
            const float gv = 0.5f * u * (1.0f + erff(u * 0.70710678118654752f));
            ob0[(size_t)grow * 896 + 832 + (col - 64)] = f2bf(gv);
          } else if (col < 200) {
            const float z = v + p1[col - 128];
            of0[(size_t)grow * 72 + (col - 128)] = 1.0f / (1.0f + expf(-z));
          }
        }
    }
  } else if constexpr (MODE == 1) {
#pragma unroll
    for (int fc = 0; fc < 4; ++fc) {
      const int col = bc * 128 + wcol + fc * 16 + rl;
      const float bb = p0[col], sc = p1[col], sf = p2[col];
#pragma unroll
      for (int fr = 0; fr < 4; ++fr)
#pragma unroll
        for (int r = 0; r < 4; ++r) {
          const int grow = br * 128 + wrow + fr * 16 + gq * 4 + r;
          of0[(size_t)grow * 768 + col] = (acc[fr][fc][r] + bb) * sc + sf;
        }
    }
  } else {
    const int wsel = w & 1;
    const int bq = br >> 2;            // 256-row tiles: 4 per sequence
    const int n0 = (br & 3) * 256;
    const int cbase = bc * 128 + wcol;
    const int hh = (cbase % 768) / 64;
    float s1v[4], buv[4];
#pragma unroll
    for (int fc = 0; fc < 4; ++fc) {
      const int col = cbase + fc * 16 + rl;
      s1v[fc] = p0[col];
      buv[fc] = (tq > 0) ? p1[col] : 0.0f;
    }
    if (tq < 2) {
      u16* L = (u16*)&lds[0][0] + (size_t)w * 4096;
      u16* dst = (tq == 0) ? ob0 : ob1;
      const float osc = (tq == 0) ? 0.125f : 1.0f;
#pragma unroll
      for (int fr = 0; fr < 4; ++fr)
#pragma unroll
        for (int r = 0; r < 4; ++r) {
          const int nloc = fr * 16 + gq * 4 + r;
          const float gp = glds[wsel][1][wrow + nloc];
#pragma unroll
          for (int fc = 0; fc < 4; ++fc) {
            const int d = fc * 16 + rl;
            const float v = (acc[fr][fc][r] + s1v[fc] + gp * buv[fc]) * osc;
            L[nloc * 64 + (d ^ (gq << 4))] = f2bf(v);
          }
        }
      const size_t rowbase = (size_t)(bq * 12 + hh) * 1024 + n0 + wrow;
#pragma unroll
      for (int it = 0; it < 8; ++it) {
        const int nloc = it * 8 + (l >> 3);
        const int sl8 = l & 7;
        const s16x8 val =
            *(const s16x8*)&L[nloc * 64 + ((sl8 * 8) ^ (((nloc >> 2) & 3) << 4))];
        *(s16x8*)(dst + (rowbase + nloc) * 64 + sl8 * 8) = val;
      }
    } else {
      u16* L = (u16*)&lds[0][0] + (size_t)w * 4096;
#pragma unroll
      for (int fr = 0; fr < 4; ++fr)
#pragma unroll
        for (int r = 0; r < 4; ++r) {
          const int rloc = wrow + fr * 16 + gq * 4 + r;
          const float gp = glds[wsel][1][rloc];
          const int nloc = fr * 16 + gq * 4 + r;
#pragma unroll
          for (int fc = 0; fc < 4; ++fc) {
            const int d = fc * 16 + rl;
            const float v = acc[fr][fc][r] + s1v[fc] + gp * buv[fc];
            L[(d * 64 + nloc) ^ ((d & 7) << 3)] = f2bf(v);
          }
        }
      const int nw = n0 + wrow;
#pragma unroll
      for (int it = 0; it < 8; ++it) {
        const int d = it * 8 + (l >> 3);
        const int slot = l & 7;
        const s16x8 val = *(const s16x8*)&L[d * 64 + ((slot ^ (d & 7)) << 3)];
        *(s16x8*)(ob2 + ((size_t)(bq * 12 + hh) * 64 + d) * 1024 + nw + slot * 8) = val;
      }
    }
  }
}

// ---------------------------------------------------------------- attention
// Swapped-QK^T 32x32; 3-buffer depth-2 counted-vmcnt pipeline (proven shape).

__global__ __launch_bounds__(256)
void attn2_kernel(const u16* __restrict__ Q, const u16* __restrict__ K,
                  const u16* __restrict__ VT, u16* __restrict__ AO) {
  __shared__ __align__(16) u16 kv[3][8192];  // [buf][ K 64x64 | VT 64x64 ]
  const int tid = threadIdx.x, w = tid >> 6, l = tid & 63;
  const int l31 = l & 31, hi = l >> 5;
  const int bh = blockIdx.x % 96, qt = blockIdx.x / 96;
  const size_t kb = (size_t)bh * (1024 * 64);
  const float LOG2E = 1.4426950408889634f;
  const float THR = 5.545177f;

  const int q0 = qt * 128 + w * 32;
  s16x8 qf[4];
  {
    const u16* qp = Q + kb + (size_t)(q0 + l31) * 64 + hi * 8;
#pragma unroll
    for (int ks = 0; ks < 4; ++ks) qf[ks] = *(const s16x8*)(qp + ks * 16);
  }

  const int srow = l >> 3;
  const int sslot = (l & 7) ^ srow;
  const u16* kSrc = K + kb + (size_t)(w * 16 + srow) * 64 + sslot * 8;
  const u16* vSrc = VT + kb + (size_t)(w * 16 + srow) * 1024 + sslot * 8;
  auto stage = [&](int t, int buf) {
    const int kv0 = t * 64;
    GLD16(kSrc + (size_t)kv0 * 64, &kv[buf][(w * 16) * 64]);
    GLD16(kSrc + (size_t)kv0 * 64 + 8 * 64, &kv[buf][(w * 16 + 8) * 64]);
    GLD16(vSrc + kv0, &kv[buf][4096 + (w * 16) * 64]);
    GLD16(vSrc + kv0 + 8 * 1024, &kv[buf][4096 + (w * 16 + 8) * 64]);
  };

  f32x16 o0, o1;
#pragma unroll
  for (int r = 0; r < 16; ++r) { o0[r] = 0.f; o1[r] = 0.f; }
  float m = -1.0e30f, lsum = 0.f;

  const int swz = l31 & 7;

  stage(0, 0);
  stage(1, 1);

  for (int t = 0; t < 16; ++t) {
    const int buf = t % 3;
    if (t + 2 < 16) stage(t + 2, (t + 2) % 3);
    if (t < 14)       WAITVM(8);
    else if (t == 14) WAITVM(4);
    else              WAITVM(0);
    SBAR();

    // ---- QK^T: S^T[kv][q]; lane q-col = l31; kv(r,hi) = (r&3)+8*(r>>2)+4*hi
    f32x16 sA, sB;
#pragma unroll
    for (int r = 0; r < 16; ++r) { sA[r] = 0.f; sB[r] = 0.f; }
#pragma unroll
    for (int ks = 0; ks < 4; ++ks) {
      const int slot = (ks * 2 + hi) ^ swz;
      const s16x8 k0 = *(const s16x8*)&kv[buf][l31 * 64 + slot * 8];
      const s16x8 k1 = *(const s16x8*)&kv[buf][(32 + l31) * 64 + slot * 8];
      sA = MFMA32(k0, qf[ks], sA);
      sB = MFMA32(k1, qf[ks], sB);
    }

    // ---- online softmax (per-lane: one q = l31)
    float pm = sA[0];
#pragma unroll
    for (int r = 1; r < 16; ++r) pm = fmaxf(pm, sA[r]);
#pragma unroll
    for (int r = 0; r < 16; ++r) pm = fmaxf(pm, sB[r]);
    pm = xor32_max(pm);

    const bool need = pm > m + THR;
    if (__any(need)) {
      const float mnew = need ? pm : m;
      const float corr = __builtin_amdgcn_exp2f((m - mnew) * LOG2E);
      m = mnew;
      lsum *= corr;
#pragma unroll
      for (int r = 0; r < 16; ++r) {
        const int qrow = (r & 3) + 8 * (r >> 2) + 4 * hi;
        const float cr = __shfl(corr, qrow, 64);
        o0[r] *= cr; o1[r] *= cr;
      }
    }

    const float mL = m * LOG2E;
    float ps = 0.f;
#pragma unroll
    for (int r = 0; r < 16; ++r) {
      const float p = __builtin_amdgcn_exp2f(__builtin_fmaf(sA[r], LOG2E, -mL));
      sA[r] = p; ps += p;
    }
#pragma unroll
    for (int r = 0; r < 16; ++r) {
      const float p = __builtin_amdgcn_exp2f(__builtin_fmaf(sB[r], LOG2E, -mL));
      sB[r] = p; ps += p;
    }
    lsum += xor32_sum(ps);

    // ---- P -> bf16 A-fragments via perm-pack + shfl_xor(32) + per-half select
    s16x8 pf[4];
#pragma unroll
    for (int s = 0; s < 4; ++s) {
      const f32x16 P = (s < 2) ? sA : sB;
      const int b = 8 * (s & 1);
      const u32 A0 = pkbf_hu(P[b + 0], P[b + 1]);
      const u32 A1 = pkbf_hu(P[b + 2], P[b + 3]);
      const u32 A2 = pkbf_hu(P[b + 4], P[b + 5]);
      const u32 A3 = pkbf_hu(P[b + 6], P[b + 7]);
      const u32 B0 = (u32)__shfl_xor((int)A0, 32, 64);
      const u32 B1 = (u32)__shfl_xor((int)A1, 32, 64);
      const u32 B2 = (u32)__shfl_xor((int)A2, 32, 64);
      const u32 B3 = (u32)__shfl_xor((int)A3, 32, 64);
      union { u32 u[4]; s16x8 v; } pk;
      pk.u[0] = hi ? B2 : A0;
      pk.u[1] = hi ? B3 : A1;
      pk.u[2] = hi ? A2 : B0;
      pk.u[3] = hi ? A3 : B1;
      pf[s] = pk.v;
    }

    // ---- PV
#pragma unroll
    for (int s = 0; s < 4; ++s) {
      const int slot = (s * 2 + hi) ^ swz;
      const s16x8 v0 = *(const s16x8*)&kv[buf][4096 + l31 * 64 + slot * 8];
      const s16x8 v1 = *(const s16x8*)&kv[buf][4096 + (32 + l31) * 64 + slot * 8];
      o0 = MFMA32(pf[s], v0, o0);
      o1 = MFMA32(pf[s], v1, o1);
    }
    SBAR();
  }

  // ---- epilogue
  const float invl = 1.0f / lsum;
  const int bq = bh / 12, h = bh % 12;
#pragma unroll
  for (int r = 0; r < 16; ++r) {
    const int qrow = (r & 3) + 8 * (r >> 2) + 4 * hi;
    const float ir = __shfl(invl, qrow, 64);
    const int n = q0 + qrow;
    u16* dst = AO + ((size_t)bq * 1024 + n) * 768 + h * 64 + l31;
    dst[0]  = f2bf(o0[r] * ir);
    dst[32] = f2bf(o1[r] * ir);
  }
}

// ---------------------------------------------------------------- launch

extern "C" void kernel_launch(void* const* d_in, const int* in_sizes, int n_in,
                              void* d_out, int out_size, void* d_ws, size_t ws_size,
                              hipStream_t stream) {
  (void)in_sizes; (void)n_in; (void)out_size; (void)ws_size;
  const float* x    = (const float*)d_in[0];
  const float* Wqkv = (const float*)d_in[1];
  const float* s1   = (const float*)d_in[2];
  const float* sh1  = (const float*)d_in[3];
  const float* Wa   = (const float*)d_in[4];
  const float* Wb   = (const float*)d_in[5];
  const float* Wr   = (const float*)d_in[6];
  const float* brt  = (const float*)d_in[7];
  const float* Wdn  = (const float*)d_in[8];
  const float* bdn  = (const float*)d_in[9];
  const float* Wup  = (const float*)d_in[10];
  const float* bup  = (const float*)d_in[11];
  const float* Wp   = (const float*)d_in[12];
  const float* bpj  = (const float*)d_in[13];
  const float* sc2  = (const float*)d_in[14];
  const float* sf2  = (const float*)d_in[15];
  float* out = (float*)d_out;

  char* ws = (char*)d_ws;
  size_t off = 0;
  auto take = [&](size_t bytes) -> void* {
    void* p = ws + off;
    off = (off + bytes + 255) & ~(size_t)255;
    return p;
  };
  u16* Aaug = (u16*)take(8192UL * 896 * 2);
  u16* Baug = (u16*)take(2304UL * 896 * 2);
  u16* Wsm  = (u16*)take(256UL * 768 * 2);
  u16* Wpj  = (u16*)take(768UL * 768 * 2);
  float* gates = (float*)take(8192UL * 72 * 4);
  u16* qb  = (u16*)take(96UL * 1024 * 64 * 2);
  u16* kbf = (u16*)take(96UL * 1024 * 64 * 2);
  u16* vtb = (u16*)take(96UL * 64 * 1024 * 2);
  u16* ao  = (u16*)take(8192UL * 768 * 2);

  prep_x<<<dim3(6144), dim3(256), 0, stream>>>(x, Aaug);
  prep_w<<<dim3(11136), dim3(256), 0, stream>>>(Wqkv, s1, Wb, Wup, Wa, Wdn, Wr, Wp,
                                                Baug, Wsm, Wpj);
  gemm_mfma<0><<<dim3(64, 2), dim3(256), 0, stream>>>(
      Aaug, 896, Wsm, 768, bdn, brt, nullptr, Aaug, nullptr, nullptr, gates, nullptr);
  gemm_mfma<2><<<dim3(32, 18), dim3(512), 0, stream>>>(
      Aaug, 896, Baug, 896, sh1, bup, nullptr, qb, kbf, vtb, nullptr, gates);
  attn2_kernel<<<dim3(768), dim3(256), 0, stream>>>(qb, kbf, vtb, ao);
  gemm_mfma<1><<<dim3(64, 6), dim3(256), 0, stream>>>(
      ao, 768, Wpj, 768, bpj, sc2, sf2, nullptr, nullptr, nullptr, out, nullptr);
}

// Round 14
// 174.269 us; speedup vs baseline: 1.1135x; 1.0319x over previous
//
#include <hip/hip_runtime.h>
#include <math.h>

typedef unsigned short u16;
typedef unsigned int u32;
typedef short s16x8 __attribute__((ext_vector_type(8)));
typedef float f32x4 __attribute__((ext_vector_type(4)));
typedef float f32x16 __attribute__((ext_vector_type(16)));
typedef u16 u16x4 __attribute__((ext_vector_type(4)));

#define DEVI __device__ __forceinline__

DEVI u16 f2bf(float f) {
  unsigned u = __builtin_bit_cast(unsigned, f);
  u += 0x7fffu + ((u >> 16) & 1u);
  return (u16)(u >> 16);
}

// pack two f32 -> 2x bf16 with round-half-up (+0x8000) via one v_perm_b32
DEVI u32 pkbf_hu(float a, float b) {
  const u32 ua = __builtin_bit_cast(u32, a) + 0x8000u;
  const u32 ub = __builtin_bit_cast(u32, b) + 0x8000u;
  return __builtin_amdgcn_perm(ub, ua, 0x07060302u);
}

DEVI f32x4 zero4() { f32x4 z; z[0]=0.f; z[1]=0.f; z[2]=0.f; z[3]=0.f; return z; }

DEVI float xor32_max(float x) { return fmaxf(x, __shfl_xor(x, 32, 64)); }
DEVI float xor32_sum(float x) { return x + __shfl_xor(x, 32, 64); }

#define MFMA16(a,b,c) __builtin_amdgcn_mfma_f32_16x16x32_bf16((a),(b),(c),0,0,0)
#define MFMA32(a,b,c) __builtin_amdgcn_mfma_f32_32x32x16_bf16((a),(b),(c),0,0,0)

#define GLD16(gp, lp) __builtin_amdgcn_global_load_lds( \
  (const __attribute__((address_space(1))) void*)(const void*)(gp), \
  (__attribute__((address_space(3))) void*)(void*)(lp), 16, 0, 0)

#define WAITVM(N) asm volatile("s_waitcnt vmcnt(" #N ")" ::: "memory")
#define WAITLG0() asm volatile("s_waitcnt lgkmcnt(0)" ::: "memory")
#define SBAR() __builtin_amdgcn_s_barrier()

// ---------------------------------------------------------------- prep kernels

__global__ __launch_bounds__(256) void prep_x(const float* __restrict__ x,
                                              u16* __restrict__ Aaug) {
  const int i = blockIdx.x * 256 + threadIdx.x;
  if (i >= 8192 * 192) return;
  const int row = i / 192, c4 = (i - row * 192) * 4;
  const float4 v = *(const float4*)(x + (size_t)row * 768 + c4);
  u16x4 o; o[0]=f2bf(v.x); o[1]=f2bf(v.y); o[2]=f2bf(v.z); o[3]=f2bf(v.w);
  *(u16x4*)(Aaug + (size_t)row * 896 + c4) = o;
}

__global__ __launch_bounds__(256) void prep_w(
    const float* __restrict__ Wqkv, const float* __restrict__ s1,
    const float* __restrict__ Wb, const float* __restrict__ Wup,
    const float* __restrict__ Wa, const float* __restrict__ Wdn,
    const float* __restrict__ Wr, const float* __restrict__ Wp,
    u16* __restrict__ Baug, u16* __restrict__ Wsm, u16* __restrict__ Wpj) {
  const int i = blockIdx.x * 256 + threadIdx.x;
  const int N1 = 2304 * 896, N2 = N1 + 256 * 768, N3 = N2 + 768 * 768;
  if (i < N1) {
    const int c = i / 896, kk = i - c * 896;
    float v;
    if (kk < 768)      v = Wqkv[(size_t)c * 768 + kk] * s1[c];
    else if (kk < 832) v = Wb[(size_t)c * 64 + (kk - 768)];
    else               v = Wup[(size_t)c * 64 + (kk - 832)];
    Baug[i] = f2bf(v);
  } else if (i < N2) {
    const int j = i - N1; const int r = j / 768, kk = j - r * 768;
    float v = 0.0f;
    if (r < 64)       v = Wa[(size_t)r * 768 + kk];
    else if (r < 128) v = Wdn[(size_t)(r - 64) * 768 + kk];
    else if (r < 200) v = Wr[(size_t)(r - 128) * 768 + kk];
    Wsm[j] = f2bf(v);
  } else if (i < N3) {
    const int j = i - N2;
    Wpj[j] = f2bf(Wp[j]);
  }
}

// ---------------------------------------------------------------- GEMM kernel
// Best measured config (174.0 us total, MODE2 72 us): 3-buffer, prefetch
// depth-2, counted vmcnt, stage-BEFORE-wait, two barriers, rolled loop.
// NOTE: unroll/single-barrier/4-buf/2-buf/256-row-tile/XCD-swizzle all
// measured WORSE (r7-r13). Do not repeat.

template <int MODE>
__global__ __launch_bounds__(256)
void gemm_mfma(const u16* __restrict__ A, int lda,
               const u16* __restrict__ Bt, int ldb,
               const float* __restrict__ p0, const float* __restrict__ p1,
               const float* __restrict__ p2,
               u16* __restrict__ ob0, u16* __restrict__ ob1, u16* __restrict__ ob2,
               float* __restrict__ of0,
               const float* __restrict__ gates) {
  __shared__ __align__(16) u16 lds[3][8192];
  __shared__ float glds[2][2][128];
  const int tid = threadIdx.x;
  const int w = tid >> 6, l = tid & 63;
  const int rl = l & 15, gq = l >> 4;
  const int wrow = (w >> 1) * 64, wcol = (w & 1) * 64;
  const int br = blockIdx.x, bc = blockIdx.y;
  const int nt = (MODE == 2) ? 28 : 24;

  const int srow = l >> 2;
  const int sslot = (l & 3) ^ ((srow >> 1) & 3);
  const u16* aSrc = A + (size_t)(br * 128 + w * 32 + srow) * lda + sslot * 8;
  const u16* bSrc = Bt + (size_t)(bc * 128 + w * 32 + srow) * ldb + sslot * 8;

  int tq = 0;
  if constexpr (MODE == 2) {
    const int g = bc * 2 + (w & 1);
    tq = g / 12;
  }

  auto kt_of = [&](int t) {
    if constexpr (MODE == 2) return (t < 2) ? 26 + t : ((t < 4) ? 22 + t : t - 4);
    else return t;
  };
  auto stage = [&](int kt, int buf) {
    const size_t k0 = (size_t)kt * 32;
    GLD16(aSrc + k0, &lds[buf][(w * 32) * 32]);
    GLD16(aSrc + k0 + (size_t)16 * lda, &lds[buf][(w * 32 + 16) * 32]);
    GLD16(bSrc + k0, &lds[buf][4096 + (w * 32) * 32]);
    GLD16(bSrc + k0 + (size_t)16 * ldb, &lds[buf][4096 + (w * 32 + 16) * 32]);
  };

  // prologue: stage 2 tiles, gate loads (MODE2)
  stage(kt_of(0), 0);
  stage(kt_of(1), 1);
  if constexpr (MODE == 2) {
    const int gsel = tid >> 7, rr = tid & 127;
    const int gg = bc * 2 + gsel;
    const int tt = gg / 12, hh = gg % 12;
    const int f = hh * 3 + tt;
    const int ridx = (f / 12) * 24 + (f % 12) * 2;
    glds[gsel][0][rr] = gates[(size_t)(br * 128 + rr) * 72 + ridx];
    glds[gsel][1][rr] = gates[(size_t)(br * 128 + rr) * 72 + ridx + 1];
    WAITLG0();  // glds ds_writes visible before first barrier
  }

  f32x4 acc[4][4];
#pragma unroll
  for (int i = 0; i < 4; ++i)
#pragma unroll
    for (int j = 0; j < 4; ++j) acc[i][j] = zero4();

  for (int t = 0; t < nt; ++t) {
    const int buf = t % 3;
    if (t + 2 < nt) stage(kt_of(t + 2), (t + 2) % 3);
    if (t < nt - 2)       WAITVM(8);   // tile t drained; t+1,t+2 in flight
    else if (t == nt - 2) WAITVM(4);
    else                  WAITVM(0);
    SBAR();

    const int sl = gq ^ ((rl >> 1) & 3);
    s16x8 af[4], bfv[4];
#pragma unroll
    for (int fr = 0; fr < 4; ++fr) {
      const int row = wrow + fr * 16 + rl;
      af[fr] = *(const s16x8*)&lds[buf][row * 32 + sl * 8];
    }
#pragma unroll
    for (int fc = 0; fc < 4; ++fc) {
      const int row = wcol + fc * 16 + rl;
      bfv[fc] = *(const s16x8*)&lds[buf][4096 + row * 32 + sl * 8];
    }
#pragma unroll
    for (int fr = 0; fr < 4; ++fr)
#pragma unroll
      for (int fc = 0; fc < 4; ++fc)
        acc[fr][fc] = MFMA16(af[fr], bfv[fc], acc[fr][fc]);

    if constexpr (MODE == 2) {
      if (t == 1 || t == 3) {
        const int wsel = w & 1;
        const bool ad = (t == 1);
#pragma unroll
        for (int fr = 0; fr < 4; ++fr)
#pragma unroll
          for (int r = 0; r < 4; ++r) {
            const int rloc = wrow + fr * 16 + gq * 4 + r;
            const float gl = glds[wsel][0][rloc];
            float s;
            if (ad) { const float gp = glds[wsel][1][rloc]; s = (tq > 0) ? gp / gl : 0.0f; }
            else s = gl;
#pragma unroll
            for (int fc = 0; fc < 4; ++fc) acc[fr][fc][r] *= s;
          }
      }
    }
    SBAR();  // all waves done reading lds[buf] before it is restaged
  }

  if constexpr (MODE == 0) {
#pragma unroll
    for (int fc = 0; fc < 4; ++fc) {
      const int col = bc * 128 + wcol + fc * 16 + rl;
#pragma unroll
      for (int fr = 0; fr < 4; ++fr)
#pragma unroll
        for (int r = 0; r < 4; ++r) {
          const int grow = br * 128 + wrow + fr * 16 + gq * 4 + r;
          const float v = acc[fr][fc][r];
          if (col < 64) {
            ob0[(size_t)grow * 896 + 768 + col] = f2bf(v);
          } else if (col < 128) {
            const float u = v + p0[col - 64];
            const float gv = 0.5f * u * (1.0f + erff(u * 0.70710678118654752f));
            ob0[(size_t)grow * 896 + 832 + (col - 64)] = f2bf(gv);
          } else if (col < 200) {
            const float z = v + p1[col - 128];
            of0[(size_t)grow * 72 + (col - 128)] = 1.0f / (1.0f + expf(-z));
          }
        }
    }
  } else if constexpr (MODE == 1) {
#pragma unroll
    for (int fc = 0; fc < 4; ++fc) {
      const int col = bc * 128 + wcol + fc * 16 + rl;
      const float bb = p0[col], sc = p1[col], sf = p2[col];
#pragma unroll
      for (int fr = 0; fr < 4; ++fr)
#pragma unroll
        for (int r = 0; r < 4; ++r) {
          const int grow = br * 128 + wrow + fr * 16 + gq * 4 + r;
          of0[(size_t)grow * 768 + col] = (acc[fr][fc][r] + bb) * sc + sf;
        }
    }
  } else {
    const int wsel = w & 1;
    const int bq = br >> 3;
    const int n0 = (br & 7) * 128;
    const int cbase = bc * 128 + wcol;
    const int hh = (cbase % 768) / 64;
    float s1v[4], buv[4];
#pragma unroll
    for (int fc = 0; fc < 4; ++fc) {
      const int col = cbase + fc * 16 + rl;
      s1v[fc] = p0[col];
      buv[fc] = (tq > 0) ? p1[col] : 0.0f;
    }
    if (tq < 2) {
      u16* L = (u16*)&lds[0][0] + (size_t)w * 4096;
      u16* dst = (tq == 0) ? ob0 : ob1;
      const float osc = (tq == 0) ? 0.125f : 1.0f;
#pragma unroll
      for (int fr = 0; fr < 4; ++fr)
#pragma unroll
        for (int r = 0; r < 4; ++r) {
          const int nloc = fr * 16 + gq * 4 + r;
          const float gp = glds[wsel][1][wrow + nloc];
#pragma unroll
          for (int fc = 0; fc < 4; ++fc) {
            const int d = fc * 16 + rl;
            const float v = (acc[fr][fc][r] + s1v[fc] + gp * buv[fc]) * osc;
            L[nloc * 64 + (d ^ (gq << 4))] = f2bf(v);
          }
        }
      const size_t rowbase = (size_t)(bq * 12 + hh) * 1024 + n0 + wrow;
#pragma unroll
      for (int it = 0; it < 8; ++it) {
        const int nloc = it * 8 + (l >> 3);
        const int sl8 = l & 7;
        const s16x8 val =
            *(const s16x8*)&L[nloc * 64 + ((sl8 * 8) ^ (((nloc >> 2) & 3) << 4))];
        *(s16x8*)(dst + (rowbase + nloc) * 64 + sl8 * 8) = val;
      }
    } else {
      u16* L = (u16*)&lds[0][0] + (size_t)w * 4096;
#pragma unroll
      for (int fr = 0; fr < 4; ++fr)
#pragma unroll
        for (int r = 0; r < 4; ++r) {
          const int rloc = wrow + fr * 16 + gq * 4 + r;
          const float gp = glds[wsel][1][rloc];
          const int nloc = fr * 16 + gq * 4 + r;
#pragma unroll
          for (int fc = 0; fc < 4; ++fc) {
            const int d = fc * 16 + rl;
            const float v = acc[fr][fc][r] + s1v[fc] + gp * buv[fc];
            L[(d * 64 + nloc) ^ ((d & 7) << 3)] = f2bf(v);
          }
        }
      const int nw = n0 + wrow;
#pragma unroll
      for (int it = 0; it < 8; ++it) {
        const int d = it * 8 + (l >> 3);
        const int slot = l & 7;
        const s16x8 val = *(const s16x8*)&L[d * 64 + ((slot ^ (d & 7)) << 3)];
        *(s16x8*)(ob2 + ((size_t)(bq * 12 + hh) * 64 + d) * 1024 + nw + slot * 8) = val;
      }
    }
  }
}

// ---------------------------------------------------------------- attention
// Swapped-QK^T 32x32; 3-buffer depth-2 counted-vmcnt pipeline (proven shape)
// + s_setprio(1) around MFMA clusters (T5: helps attn with 3 independent
// blocks/CU at uncorrelated phases; m191 +4-7%).

__global__ __launch_bounds__(256)
void attn2_kernel(const u16* __restrict__ Q, const u16* __restrict__ K,
                  const u16* __restrict__ VT, u16* __restrict__ AO) {
  __shared__ __align__(16) u16 kv[3][8192];  // [buf][ K 64x64 | VT 64x64 ]
  const int tid = threadIdx.x, w = tid >> 6, l = tid & 63;
  const int l31 = l & 31, hi = l >> 5;
  const int bh = blockIdx.x % 96, qt = blockIdx.x / 96;
  const size_t kb = (size_t)bh * (1024 * 64);
  const float LOG2E = 1.4426950408889634f;
  const float THR = 5.545177f;

  const int q0 = qt * 128 + w * 32;
  s16x8 qf[4];
  {
    const u16* qp = Q + kb + (size_t)(q0 + l31) * 64 + hi * 8;
#pragma unroll
    for (int ks = 0; ks < 4; ++ks) qf[ks] = *(const s16x8*)(qp + ks * 16);
  }

  const int srow = l >> 3;
  const int sslot = (l & 7) ^ srow;
  const u16* kSrc = K + kb + (size_t)(w * 16 + srow) * 64 + sslot * 8;
  const u16* vSrc = VT + kb + (size_t)(w * 16 + srow) * 1024 + sslot * 8;
  auto stage = [&](int t, int buf) {
    const int kv0 = t * 64;
    GLD16(kSrc + (size_t)kv0 * 64, &kv[buf][(w * 16) * 64]);
    GLD16(kSrc + (size_t)kv0 * 64 + 8 * 64, &kv[buf][(w * 16 + 8) * 64]);
    GLD16(vSrc + kv0, &kv[buf][4096 + (w * 16) * 64]);
    GLD16(vSrc + kv0 + 8 * 1024, &kv[buf][4096 + (w * 16 + 8) * 64]);
  };

  f32x16 o0, o1;
#pragma unroll
  for (int r = 0; r < 16; ++r) { o0[r] = 0.f; o1[r] = 0.f; }
  float m = -1.0e30f, lsum = 0.f;

  const int swz = l31 & 7;

  stage(0, 0);
  stage(1, 1);

  for (int t = 0; t < 16; ++t) {
    const int buf = t % 3;
    if (t + 2 < 16) stage(t + 2, (t + 2) % 3);
    if (t < 14)       WAITVM(8);
    else if (t == 14) WAITVM(4);
    else              WAITVM(0);
    SBAR();

    // ---- QK^T: S^T[kv][q]; lane q-col = l31; kv(r,hi) = (r&3)+8*(r>>2)+4*hi
    f32x16 sA, sB;
#pragma unroll
    for (int r = 0; r < 16; ++r) { sA[r] = 0.f; sB[r] = 0.f; }
    __builtin_amdgcn_s_setprio(1);
#pragma unroll
    for (int ks = 0; ks < 4; ++ks) {
      const int slot = (ks * 2 + hi) ^ swz;
      const s16x8 k0 = *(const s16x8*)&kv[buf][l31 * 64 + slot * 8];
      const s16x8 k1 = *(const s16x8*)&kv[buf][(32 + l31) * 64 + slot * 8];
      sA = MFMA32(k0, qf[ks], sA);
      sB = MFMA32(k1, qf[ks], sB);
    }
    __builtin_amdgcn_s_setprio(0);

    // ---- online softmax (per-lane: one q = l31)
    float pm = sA[0];
#pragma unroll
    for (int r = 1; r < 16; ++r) pm = fmaxf(pm, sA[r]);
#pragma unroll
    for (int r = 0; r < 16; ++r) pm = fmaxf(pm, sB[r]);
    pm = xor32_max(pm);

    const bool need = pm > m + THR;
    if (__any(need)) {
      const float mnew = need ? pm : m;
      const float corr = __builtin_amdgcn_exp2f((m - mnew) * LOG2E);
      m = mnew;
      lsum *= corr;
#pragma unroll
      for (int r = 0; r < 16; ++r) {
        const int qrow = (r & 3) + 8 * (r >> 2) + 4 * hi;
        const float cr = __shfl(corr, qrow, 64);
        o0[r] *= cr; o1[r] *= cr;
      }
    }

    const float mL = m * LOG2E;
    float ps = 0.f;
#pragma unroll
    for (int r = 0; r < 16; ++r) {
      const float p = __builtin_amdgcn_exp2f(__builtin_fmaf(sA[r], LOG2E, -mL));
      sA[r] = p; ps += p;
    }
#pragma unroll
    for (int r = 0; r < 16; ++r) {
      const float p = __builtin_amdgcn_exp2f(__builtin_fmaf(sB[r], LOG2E, -mL));
      sB[r] = p; ps += p;
    }
    lsum += xor32_sum(ps);

    // ---- P -> bf16 A-fragments via perm-pack + shfl_xor(32) + per-half select
    s16x8 pf[4];
#pragma unroll
    for (int s = 0; s < 4; ++s) {
      const f32x16 P = (s < 2) ? sA : sB;
      const int b = 8 * (s & 1);
      const u32 A0 = pkbf_hu(P[b + 0], P[b + 1]);
      const u32 A1 = pkbf_hu(P[b + 2], P[b + 3]);
      const u32 A2 = pkbf_hu(P[b + 4], P[b + 5]);
      const u32 A3 = pkbf_hu(P[b + 6], P[b + 7]);
      const u32 B0 = (u32)__shfl_xor((int)A0, 32, 64);
      const u32 B1 = (u32)__shfl_xor((int)A1, 32, 64);
      const u32 B2 = (u32)__shfl_xor((int)A2, 32, 64);
      const u32 B3 = (u32)__shfl_xor((int)A3, 32, 64);
      union { u32 u[4]; s16x8 v; } pk;
      pk.u[0] = hi ? B2 : A0;
      pk.u[1] = hi ? B3 : A1;
      pk.u[2] = hi ? A2 : B0;
      pk.u[3] = hi ? A3 : B1;
      pf[s] = pk.v;
    }

    // ---- PV
    __builtin_amdgcn_s_setprio(1);
#pragma unroll
    for (int s = 0; s < 4; ++s) {
      const int slot = (s * 2 + hi) ^ swz;
      const s16x8 v0 = *(const s16x8*)&kv[buf][4096 + l31 * 64 + slot * 8];
      const s16x8 v1 = *(const s16x8*)&kv[buf][4096 + (32 + l31) * 64 + slot * 8];
      o0 = MFMA32(pf[s], v0, o0);
      o1 = MFMA32(pf[s], v1, o1);
    }
    __builtin_amdgcn_s_setprio(0);
    SBAR();
  }

  // ---- epilogue
  const float invl = 1.0f / lsum;
  const int bq = bh / 12, h = bh % 12;
#pragma unroll
  for (int r = 0; r < 16; ++r) {
    const int qrow = (r & 3) + 8 * (r >> 2) + 4 * hi;
    const float ir = __shfl(invl, qrow, 64);
    const int n = q0 + qrow;
    u16* dst = AO + ((size_t)bq * 1024 + n) * 768 + h * 64 + l31;
    dst[0]  = f2bf(o0[r] * ir);
    dst[32] = f2bf(o1[r] * ir);
  }
}

// ---------------------------------------------------------------- launch

extern "C" void kernel_launch(void* const* d_in, const int* in_sizes, int n_in,
                              void* d_out, int out_size, void* d_ws, size_t ws_size,
                              hipStream_t stream) {
  (void)in_sizes; (void)n_in; (void)out_size; (void)ws_size;
  const float* x    = (const float*)d_in[0];
  const float* Wqkv = (const float*)d_in[1];
  const float* s1   = (const float*)d_in[2];
  const float* sh1  = (const float*)d_in[3];
  const float* Wa   = (const float*)d_in[4];
  const float* Wb   = (const float*)d_in[5];
  const float* Wr   = (const float*)d_in[6];
  const float* brt  = (const float*)d_in[7];
  const float* Wdn  = (const float*)d_in[8];
  const float* bdn  = (const float*)d_in[9];
  const float* Wup  = (const float*)d_in[10];
  const float* bup  = (const float*)d_in[11];
  const float* Wp   = (const float*)d_in[12];
  const float* bpj  = (const float*)d_in[13];
  const float* sc2  = (const float*)d_in[14];
  const float* sf2  = (const float*)d_in[15];
  float* out = (float*)d_out;

  char* ws = (char*)d_ws;
  size_t off = 0;
  auto take = [&](size_t bytes) -> void* {
    void* p = ws + off;
    off = (off + bytes + 255) & ~(size_t)255;
    return p;
  };
  u16* Aaug = (u16*)take(8192UL * 896 * 2);
  u16* Baug = (u16*)take(2304UL * 896 * 2);
  u16* Wsm  = (u16*)take(256UL * 768 * 2);
  u16* Wpj  = (u16*)take(768UL * 768 * 2);
  float* gates = (float*)take(8192UL * 72 * 4);
  u16* qb  = (u16*)take(96UL * 1024 * 64 * 2);
  u16* kbf = (u16*)take(96UL * 1024 * 64 * 2);
  u16* vtb = (u16*)take(96UL * 64 * 1024 * 2);
  u16* ao  = (u16*)take(8192UL * 768 * 2);

  prep_x<<<dim3(6144), dim3(256), 0, stream>>>(x, Aaug);
  prep_w<<<dim3(11136), dim3(256), 0, stream>>>(Wqkv, s1, Wb, Wup, Wa, Wdn, Wr, Wp,
                                                Baug, Wsm, Wpj);
  gemm_mfma<0><<<dim3(64, 2), dim3(256), 0, stream>>>(
      Aaug, 896, Wsm, 768, bdn, brt, nullptr, Aaug, nullptr, nullptr, gates, nullptr);
  gemm_mfma<2><<<dim3(64, 18), dim3(256), 0, stream>>>(
      Aaug, 896, Baug, 896, sh1, bup, nullptr, qb, kbf, vtb, nullptr, gates);
  attn2_kernel<<<dim3(768), dim3(256), 0, stream>>>(qb, kbf, vtb, ao);
  gemm_mfma<1><<<dim3(64, 6), dim3(256), 0, stream>>>(
      ao, 768, Wpj, 768, bpj, sc2, sf2, nullptr, nullptr, nullptr, out, nullptr);
}